// Round 6
// baseline (362.518 us; speedup 1.0000x reference)
//
#include <hip/hip_runtime.h>

#define N_NODES 50000
#define N_EDGES 600000

typedef short bf16x8 __attribute__((ext_vector_type(8)));
typedef float f32x4  __attribute__((ext_vector_type(4)));
typedef unsigned short u16x8 __attribute__((ext_vector_type(8)));
typedef unsigned short u16x4 __attribute__((ext_vector_type(4)));

// ---------------- bf16 helpers (RNE) ----------------
__device__ inline ushort rne_bf16(float a) {
    union { float f; unsigned u; } v; v.f = a;
    return (ushort)((v.u + 0x7FFFu + ((v.u >> 16) & 1u)) >> 16);
}
__device__ inline float bf16_to_f32(ushort h) {
    return __uint_as_float((unsigned)h << 16);
}
__device__ inline void split_bf16(float a, ushort& hi, ushort& lo) {
    hi = rne_bf16(a);
    float hv = bf16_to_f32(hi);
    lo = rne_bf16(a - hv);
}

// ---------------- CSR build ----------------

__global__ void count_deg_kernel(const int* __restrict__ dst, int* __restrict__ deg, int ne) {
    int e = blockIdx.x * blockDim.x + threadIdx.x;
    if (e < ne) atomicAdd(&deg[dst[e]], 1);
}

__global__ __launch_bounds__(256) void block_sums_kernel(const int* __restrict__ deg,
                                                         int* __restrict__ bsum, int n) {
    __shared__ int s[256];
    int t = threadIdx.x;
    int i = blockIdx.x * 256 + t;
    s[t] = (i < n) ? deg[i] : 0;
    __syncthreads();
    #pragma unroll
    for (int d = 128; d > 0; d >>= 1) {
        if (t < d) s[t] += s[t + d];
        __syncthreads();
    }
    if (t == 0) bsum[blockIdx.x] = s[0];
}

__global__ __launch_bounds__(256) void scan_bsums_kernel(const int* __restrict__ bsum,
                                                         int* __restrict__ base, int nb,
                                                         int* __restrict__ off, int n) {
    __shared__ int s[256];
    int t = threadIdx.x;
    int v = (t < nb) ? bsum[t] : 0;
    s[t] = v;
    __syncthreads();
    #pragma unroll
    for (int d = 1; d < 256; d <<= 1) {
        int x = (t >= d) ? s[t - d] : 0;
        __syncthreads();
        s[t] += x;
        __syncthreads();
    }
    if (t < nb) base[t] = s[t] - v;
    if (t == 255) off[n] = s[255];
}

__global__ __launch_bounds__(256) void scatter_offsets_kernel(const int* __restrict__ deg,
                                                              const int* __restrict__ base,
                                                              int* __restrict__ off,
                                                              int* __restrict__ cur, int n) {
    __shared__ int s[256];
    int t = threadIdx.x;
    int i = blockIdx.x * 256 + t;
    int v = (i < n) ? deg[i] : 0;
    s[t] = v;
    __syncthreads();
    #pragma unroll
    for (int d = 1; d < 256; d <<= 1) {
        int x = (t >= d) ? s[t - d] : 0;
        __syncthreads();
        s[t] += x;
        __syncthreads();
    }
    if (i < n) {
        int excl = s[t] - v + base[blockIdx.x];
        off[i] = excl;
        cur[i] = excl;
    }
}

__global__ void fill_csr_kernel(const int* __restrict__ src, const int* __restrict__ dst,
                                int* __restrict__ cur, int* __restrict__ ssrc, int ne) {
    int e = blockIdx.x * blockDim.x + threadIdx.x;
    if (e < ne) {
        int p = atomicAdd(&cur[dst[e]], 1);
        ssrc[p] = src[e];
    }
}

// ---------------- weight pre-convert ----------------
__global__ void convert_w_kernel(const float* __restrict__ Ws, const float* __restrict__ Wn,
                                 int dout, ushort* __restrict__ Bth, ushort* __restrict__ Btl) {
    int n = blockIdx.x;
    int k = threadIdx.x;
    float w = (n < dout) ? Ws[(long)k * dout + n] : Wn[(long)k * dout + (n - dout)];
    ushort hi, lo;
    split_bf16(w, hi, lo);
    Bth[n * 128 + k] = hi;
    Btl[n * 128 + k] = lo;
}

// ---------------- split-bf16 MFMA dual GEMM — no LDS, no barriers ----------------
// S = A@Ws + bias (fp32), T = A@Wn (stored bf16 for the cheap gather).
// A-fragments loaded straight from global in MFMA layout (row=lane&15, k=quad*8..+8),
// split to hi/lo bf16 in registers. B-fragments from the tiny L2-hot Bt tables.
// MFMA issue order per accumulator identical to the LDS version -> bitwise-same output.

#define KDIM 128

__device__ inline void load_split_a(const float* __restrict__ A, int row, int M, int k0,
                                    int quad, bf16x8& ah, bf16x8& al) {
    float f[8];
    if (row < M) {
        const float* ap = A + (long)row * KDIM + k0 + quad * 8;
        float4 a0 = *(const float4*)ap;
        float4 a1 = *(const float4*)(ap + 4);
        f[0] = a0.x; f[1] = a0.y; f[2] = a0.z; f[3] = a0.w;
        f[4] = a1.x; f[5] = a1.y; f[6] = a1.z; f[7] = a1.w;
    } else {
        #pragma unroll
        for (int i = 0; i < 8; ++i) f[i] = 0.f;
    }
    #pragma unroll
    for (int i = 0; i < 8; ++i) {
        ushort h, l;
        split_bf16(f[i], h, l);
        ah[i] = (short)h;
        al[i] = (short)l;
    }
}

// Layers 0/1: NCOL=256. Block = 64 rows x 256 cols; wave w -> cols [64w, 64w+64).
__global__ __launch_bounds__(256) void gemm_mfma_wide(
    const float* __restrict__ A,
    const ushort* __restrict__ Bth, const ushort* __restrict__ Btl,
    const float* __restrict__ bias,
    float* __restrict__ S, ushort* __restrict__ T, int M)
{
    const int tid = threadIdx.x;
    const int bm = blockIdx.x * 64;
    const int wave = tid >> 6;
    const int lane = tid & 63;
    const int lane16 = lane & 15;
    const int quad = lane >> 4;
    const int colbase = wave * 64;

    f32x4 acc[4][4] = {};   // [row tile][col tile]

    #pragma unroll
    for (int c = 0; c < 4; ++c) {
        const int k0 = c * 32;
        bf16x8 ah[4], al[4];
        #pragma unroll
        for (int rt = 0; rt < 4; ++rt)
            load_split_a(A, bm + 16 * rt + lane16, M, k0, quad, ah[rt], al[rt]);

        #pragma unroll
        for (int ct = 0; ct < 4; ++ct) {
            int col = colbase + 16 * ct + lane16;
            long boff = (long)col * KDIM + k0 + quad * 8;
            bf16x8 bh = *(const bf16x8*)(Bth + boff);
            bf16x8 bl = *(const bf16x8*)(Btl + boff);
            #pragma unroll
            for (int rt = 0; rt < 4; ++rt) {
                acc[rt][ct] = __builtin_amdgcn_mfma_f32_16x16x32_bf16(ah[rt], bh, acc[rt][ct], 0, 0, 0);
                acc[rt][ct] = __builtin_amdgcn_mfma_f32_16x16x32_bf16(ah[rt], bl, acc[rt][ct], 0, 0, 0);
                acc[rt][ct] = __builtin_amdgcn_mfma_f32_16x16x32_bf16(al[rt], bh, acc[rt][ct], 0, 0, 0);
            }
        }
    }

    #pragma unroll
    for (int ct = 0; ct < 4; ++ct) {
        int col = colbase + 16 * ct + lane16;
        bool toS = col < 128;
        float bv = toS ? bias[col] : 0.f;
        int tcol = toS ? col : col - 128;
        #pragma unroll
        for (int rt = 0; rt < 4; ++rt) {
            #pragma unroll
            for (int i = 0; i < 4; ++i) {
                int row = bm + 16 * rt + quad * 4 + i;
                if (row < M) {
                    if (toS) S[(long)row * 128 + tcol] = acc[rt][ct][i] + bv;
                    else     T[(long)row * 128 + tcol] = rne_bf16(acc[rt][ct][i]);
                }
            }
        }
    }
}

// Layer 2: NCOL=80. Wave w -> rows bm+16w..+16, all 80 cols (5 col tiles).
__global__ __launch_bounds__(256) void gemm_mfma_narrow(
    const float* __restrict__ A,
    const ushort* __restrict__ Bth, const ushort* __restrict__ Btl,
    const float* __restrict__ bias,
    float* __restrict__ S, ushort* __restrict__ T, int M)
{
    const int tid = threadIdx.x;
    const int bm = blockIdx.x * 64;
    const int wave = tid >> 6;
    const int lane = tid & 63;
    const int lane16 = lane & 15;
    const int quad = lane >> 4;

    f32x4 acc[5] = {};

    #pragma unroll
    for (int c = 0; c < 4; ++c) {
        const int k0 = c * 32;
        bf16x8 ah, al;
        load_split_a(A, bm + 16 * wave + lane16, M, k0, quad, ah, al);

        #pragma unroll
        for (int ct = 0; ct < 5; ++ct) {
            int col = 16 * ct + lane16;
            long boff = (long)col * KDIM + k0 + quad * 8;
            bf16x8 bh = *(const bf16x8*)(Bth + boff);
            bf16x8 bl = *(const bf16x8*)(Btl + boff);
            acc[ct] = __builtin_amdgcn_mfma_f32_16x16x32_bf16(ah, bh, acc[ct], 0, 0, 0);
            acc[ct] = __builtin_amdgcn_mfma_f32_16x16x32_bf16(ah, bl, acc[ct], 0, 0, 0);
            acc[ct] = __builtin_amdgcn_mfma_f32_16x16x32_bf16(al, bh, acc[ct], 0, 0, 0);
        }
    }

    #pragma unroll
    for (int ct = 0; ct < 5; ++ct) {
        int col = 16 * ct + lane16;
        bool toS = col < 40;
        float bv = toS ? bias[col] : 0.f;
        int tcol = toS ? col : col - 40;
        #pragma unroll
        for (int i = 0; i < 4; ++i) {
            int row = bm + 16 * wave + quad * 4 + i;
            if (row < M) {
                if (toS) S[(long)row * 40 + tcol] = acc[ct][i] + bv;
                else     T[(long)row * 40 + tcol] = rne_bf16(acc[ct][i]);
            }
        }
    }
}

// ---------------- aggregation, wave-per-node, bf16 gather ----------------

template <int RELU>
__global__ __launch_bounds__(256) void agg128_kernel(
    const float* __restrict__ S, const ushort* __restrict__ T,
    const int* __restrict__ off, const int* __restrict__ ssrc,
    float* __restrict__ out, int nnodes)
{
    const int node = (blockIdx.x * 256 + threadIdx.x) >> 6;
    if (node >= nnodes) return;
    const int lane = threadIdx.x & 63;
    const int slot = lane >> 4;          // 0..3
    const int col8 = (lane & 15) * 8;    // 8 features per lane

    const int a = off[node];
    const int b = off[node + 1];

    f32x4 acc0a = {0,0,0,0}, acc0b = {0,0,0,0};
    f32x4 acc1a = {0,0,0,0}, acc1b = {0,0,0,0};

    int i = a;
    for (; i + 8 <= b; i += 8) {
        int s0 = ssrc[i + slot];
        int s1 = ssrc[i + 4 + slot];
        u16x8 v0 = *(const u16x8*)(T + (long)s0 * 128 + col8);
        u16x8 v1 = *(const u16x8*)(T + (long)s1 * 128 + col8);
        #pragma unroll
        for (int j = 0; j < 4; ++j) {
            acc0a[j] += bf16_to_f32(v0[j]);
            acc0b[j] += bf16_to_f32(v0[4 + j]);
            acc1a[j] += bf16_to_f32(v1[j]);
            acc1b[j] += bf16_to_f32(v1[4 + j]);
        }
    }
    for (; i < b; i += 4) {
        int e = i + slot;
        if (e < b) {
            int s = ssrc[e];
            u16x8 v = *(const u16x8*)(T + (long)s * 128 + col8);
            #pragma unroll
            for (int j = 0; j < 4; ++j) {
                acc0a[j] += bf16_to_f32(v[j]);
                acc0b[j] += bf16_to_f32(v[4 + j]);
            }
        }
    }
    f32x4 accA = acc0a + acc1a;
    f32x4 accB = acc0b + acc1b;

    #pragma unroll
    for (int m = 16; m <= 32; m <<= 1) {
        #pragma unroll
        for (int j = 0; j < 4; ++j) {
            accA[j] += __shfl_xor((float)accA[j], m);
            accB[j] += __shfl_xor((float)accB[j], m);
        }
    }

    if (slot == 0) {
        int deg = b - a;
        float scale = (deg > 0) ? (1.0f / (float)deg) : 0.f;
        f32x4 sA = *(const f32x4*)(S + (long)node * 128 + col8);
        f32x4 sB = *(const f32x4*)(S + (long)node * 128 + col8 + 4);
        f32x4 rA = sA + accA * scale;
        f32x4 rB = sB + accB * scale;
        if (RELU) {
            #pragma unroll
            for (int j = 0; j < 4; ++j) {
                rA[j] = fmaxf(rA[j], 0.f);
                rB[j] = fmaxf(rB[j], 0.f);
            }
        }
        *(f32x4*)(out + (long)node * 128 + col8) = rA;
        *(f32x4*)(out + (long)node * 128 + col8 + 4) = rB;
    }
}

template <int RELU>
__global__ __launch_bounds__(256) void agg40_kernel(
    const float* __restrict__ S, const ushort* __restrict__ T,
    const int* __restrict__ off, const int* __restrict__ ssrc,
    float* __restrict__ out, int nnodes)
{
    const int node = (blockIdx.x * 256 + threadIdx.x) >> 6;
    if (node >= nnodes) return;
    const int lane = threadIdx.x & 63;
    const bool active = lane < 60;
    const int slot = active ? (lane / 10) : 5;   // 0..5
    const int fi = lane % 10;
    const int fo = fi * 4;

    const int a = off[node];
    const int b = off[node + 1];

    f32x4 acc0 = {0,0,0,0}, acc1 = {0,0,0,0};

    int i = a;
    for (; i + 12 <= b; i += 12) {
        int s0 = ssrc[i + slot];
        int s1 = ssrc[i + 6 + slot];
        u16x4 v0 = *(const u16x4*)(T + (long)s0 * 40 + fo);
        u16x4 v1 = *(const u16x4*)(T + (long)s1 * 40 + fo);
        if (active) {
            #pragma unroll
            for (int j = 0; j < 4; ++j) {
                acc0[j] += bf16_to_f32(v0[j]);
                acc1[j] += bf16_to_f32(v1[j]);
            }
        }
    }
    for (; i < b; i += 6) {
        int e = i + slot;
        if (active && e < b) {
            int s = ssrc[e];
            u16x4 v = *(const u16x4*)(T + (long)s * 40 + fo);
            #pragma unroll
            for (int j = 0; j < 4; ++j) acc0[j] += bf16_to_f32(v[j]);
        }
    }
    f32x4 acc = acc0 + acc1;

    f32x4 tot = acc;
    #pragma unroll
    for (int d = 10; d <= 50; d += 10) {
        int srcl = fi + d;
        #pragma unroll
        for (int j = 0; j < 4; ++j) tot[j] += __shfl((float)acc[j], srcl);
    }

    if (lane < 10) {
        int deg = b - a;
        float scale = (deg > 0) ? (1.0f / (float)deg) : 0.f;
        f32x4 s4 = *(const f32x4*)(S + (long)node * 40 + fo);
        f32x4 r = s4 + tot * scale;
        if (RELU) {
            #pragma unroll
            for (int j = 0; j < 4; ++j) r[j] = fmaxf(r[j], 0.f);
        }
        *(f32x4*)(out + (long)node * 40 + fo) = r;
    }
}

// ---------------- launch ----------------

extern "C" void kernel_launch(void* const* d_in, const int* in_sizes, int n_in,
                              void* d_out, int out_size, void* d_ws, size_t ws_size,
                              hipStream_t stream) {
    const float* feat = (const float*)d_in[0];
    const int*   src  = (const int*)d_in[1];
    const int*   dst  = (const int*)d_in[2];
    const float* ws0  = (const float*)d_in[3];
    const float* wn0  = (const float*)d_in[4];
    const float* b0   = (const float*)d_in[5];
    const float* ws1  = (const float*)d_in[6];
    const float* wn1  = (const float*)d_in[7];
    const float* b1   = (const float*)d_in[8];
    const float* ws2  = (const float*)d_in[9];
    const float* wn2  = (const float*)d_in[10];
    const float* b2   = (const float*)d_in[11];

    const int N = N_NODES;
    const int NE = N_EDGES;
    const int NB = (N + 255) / 256;  // 196

    char* ws = (char*)d_ws;
    int*    offsets = (int*)(ws + 0);
    int*    cursor  = (int*)(ws + 200704);
    int*    degi    = (int*)(ws + 401408);
    int*    bsum    = (int*)(ws + 601600);
    int*    bbase   = (int*)(ws + 602432);
    int*    ssrc    = (int*)(ws + 603648);
    ushort* Bth0 = (ushort*)(ws + 200704);   // overlap cursor/degi, written after CSR build
    ushort* Btl0 = (ushort*)(ws + 266240);
    ushort* Bth1 = (ushort*)(ws + 331776);
    ushort* Btl1 = (ushort*)(ws + 397312);
    ushort* Bth2 = (ushort*)(ws + 462848);
    ushort* Btl2 = (ushort*)(ws + 483328);
    float*  hbuf = (float*)(ws + 3003904);   // 25.6 MB fp32
    float*  sbuf = (float*)(ws + 28603904);  // 25.6 MB fp32
    ushort* tbuf = (ushort*)(ws + 54203904); // 12.8 MB bf16

    // ---- CSR build ----
    hipMemsetAsync(degi, 0, (size_t)N * sizeof(int), stream);
    count_deg_kernel<<<(NE + 255) / 256, 256, 0, stream>>>(dst, degi, NE);
    block_sums_kernel<<<NB, 256, 0, stream>>>(degi, bsum, N);
    scan_bsums_kernel<<<1, 256, 0, stream>>>(bsum, bbase, NB, offsets, N);
    scatter_offsets_kernel<<<NB, 256, 0, stream>>>(degi, bbase, offsets, cursor, N);
    fill_csr_kernel<<<(NE + 255) / 256, 256, 0, stream>>>(src, dst, cursor, ssrc, NE);

    // ---- weight pre-convert ----
    convert_w_kernel<<<256, 128, 0, stream>>>(ws0, wn0, 128, Bth0, Btl0);
    convert_w_kernel<<<256, 128, 0, stream>>>(ws1, wn1, 128, Bth1, Btl1);
    convert_w_kernel<<<80, 128, 0, stream>>>(ws2, wn2, 40, Bth2, Btl2);

    const int gx = (N + 63) / 64;        // 782 GEMM blocks
    const int ga = (N + 3) / 4;          // 12500 agg blocks (4 waves/block)

    // ---- layer 0 ----
    gemm_mfma_wide<<<gx, 256, 0, stream>>>(feat, Bth0, Btl0, b0, sbuf, tbuf, N);
    agg128_kernel<1><<<ga, 256, 0, stream>>>(sbuf, tbuf, offsets, ssrc, hbuf, N);

    // ---- layer 1 ----
    gemm_mfma_wide<<<gx, 256, 0, stream>>>(hbuf, Bth1, Btl1, b1, sbuf, tbuf, N);
    agg128_kernel<1><<<ga, 256, 0, stream>>>(sbuf, tbuf, offsets, ssrc, hbuf, N);

    // ---- layer 2 ----
    gemm_mfma_narrow<<<gx, 256, 0, stream>>>(hbuf, Bth2, Btl2, b2, sbuf, tbuf, N);
    agg40_kernel<0><<<ga, 256, 0, stream>>>(sbuf, tbuf, offsets, ssrc, (float*)d_out, N);
}